// Round 12
// baseline (402.518 us; speedup 1.0000x reference)
//
#include <hip/hip_runtime.h>
#include <hip/hip_bf16.h>

namespace {
constexpr int kNA = 4353, kNM = 3676, kNT = 8000;
constexpr int kN  = kNA + kNM + kNT;      // 16029
constexpr int kE  = 500000;
constexpr int kS  = 200000;
constexpr int kDIN = 512, kDP = 256, kDE = 128, kDC = 64;

constexpr size_t OUT_X  = (size_t)kN * kDE;            // h first
constexpr size_t OUT_HM = OUT_X + 3ull * kS;           // then x, then h_movie

constexpr size_t align256(size_t x) { return (x + 255) & ~size_t(255); }

// ---- workspace layout (~39 MB peak; 64 MB proven available) ----
constexpr size_t OFF_WPW1T = 0;                                    // 3 x 128 x 512 f32 (transposed)
constexpr size_t OFF_M9    = OFF_WPW1T + 3ull * 512 * 128 * 4;     // 9 x 128 x 16 f32
constexpr size_t OFF_W2T   = align256(OFF_M9 + 9ull * 2048 * 4);   // 128 x 128 f32 (transposed)
constexpr size_t OFF_HW1   = align256(OFF_W2T + 128ull * 128 * 4); // kN x 128
constexpr size_t OFF_H1    = OFF_HW1 + (size_t)kN * kDE * 4;       // kN x 128
constexpr size_t OFF_AGG2  = OFF_H1  + (size_t)kN * kDE * 4;       // kN x 128
constexpr size_t OFF_HN    = OFF_AGG2 + (size_t)kN * kDE * 4;      // kN x 128
constexpr size_t OFF_P     = OFF_HN  + (size_t)kN * kDE * 4;       // 3 x kN x 16
constexpr size_t OFF_ESRC  = align256(OFF_P + 3ull * kN * 16 * 4);
constexpr size_t OFF_RP    = align256(OFF_ESRC + (size_t)kE * 4);
constexpr size_t OFF_CUR   = align256(OFF_RP + (size_t)(kN + 1) * 4);
constexpr size_t WS_NEEDED = align256(OFF_CUR + (size_t)kN * 4);

// hw1 block partition (4 rows/block): A=1089, M=919, T=2000
constexpr int kBA = 1089, kBM = 919;            // cumulative: 1089, 2008, 4008
constexpr int kHW1Blocks = 4008;
constexpr int kG2Blocks  = (kN + 3) / 4;        // 4008
} // namespace

// ---- prep1: WpW1T[t][col][k] = (Wp_t @ W1)[k][col]  (folded + transposed) ----
__global__ __launch_bounds__(128) void prep1_kernel(
    const float* __restrict__ WpA, const float* __restrict__ WpM,
    const float* __restrict__ WpT, const float* __restrict__ W1,
    float* __restrict__ WpW1T)
{
    int b = blockIdx.x;               // 0..383
    int t = b >> 7;
    int k0 = (b & 127) * 4;
    const float* Wp = (t == 0) ? WpA : ((t == 1) ? WpM : WpT);
    int c = threadIdx.x;
    float acc[4] = {0.f, 0.f, 0.f, 0.f};
    for (int j = 0; j < kDP; j++) {
        float w1 = W1[j * kDE + c];
#pragma unroll
        for (int r = 0; r < 4; r++)
            acc[r] += Wp[(k0 + r) * kDP + j] * w1;       // uniform -> s_load
    }
#pragma unroll
    for (int r = 0; r < 4; r++)
        WpW1T[((size_t)t * kDE + c) * kDIN + k0 + r] = acc[r];
}

// ---- prep2: M9[g][t] (128x16) = Wh_g[0:128] (primary) or Wc_t @ Wh_g[slot:slot+64] ----
__global__ __launch_bounds__(256) void prep2_kernel(
    const float* __restrict__ WhA, const float* __restrict__ WhM,
    const float* __restrict__ WhT,
    const float* __restrict__ WcA, const float* __restrict__ WcM,
    const float* __restrict__ WcT,
    float* __restrict__ M9)
{
    int b = blockIdx.x;               // 0..8
    int g = b / 3, t = b % 3;
    const float* Wh = (g == 0) ? WhA : ((g == 1) ? WhM : WhT);
    const float* Wc = (t == 0) ? WcA : ((t == 1) ? WcM : WcT);
    int slot;
    if (t == g) slot = 0;
    else {
        int lower = (g == 0) ? 1 : 0;
        slot = (t == lower) ? 128 : 192;
    }
    float* Mout = M9 + (size_t)b * 2048;
    for (int idx = threadIdx.x; idx < 2048; idx += 256) {
        int k = idx >> 4, j = idx & 15;
        float v;
        if (slot == 0) v = Wh[k * 16 + j];
        else {
            v = 0.f;
            for (int d = 0; d < kDC; d++)
                v += Wc[k * kDC + d] * Wh[(slot + d) * 16 + j];
        }
        Mout[idx] = v;
    }
}

// ---- transpose W2 -> W2T[col][k] ----
__global__ __launch_bounds__(256) void w2t_kernel(const float* __restrict__ W2,
                                                  float* __restrict__ W2T)
{
    int idx = blockIdx.x * 256 + threadIdx.x;
    if (idx < kDE * kDE) {
        int k = idx >> 7, c = idx & 127;
        W2T[c * kDE + k] = W2[k * kDE + c];
    }
}

// ---- hw1: HW1[n][col] = dot(feat[n], WpW1T[t][col]); 4 rows/block ----
__global__ __launch_bounds__(128) void hw1_kernel(
    const float* __restrict__ hA, const float* __restrict__ hM,
    const float* __restrict__ hT, const float* __restrict__ WpW1T,
    float* __restrict__ HW1)
{
    int b = blockIdx.x;
    const float *A, *WT; int typeN, rowBase, lb;
    if (b < kBA)             { lb = b;              A = hA; WT = WpW1T;                  typeN = kNA; rowBase = 0; }
    else if (b < kBA + kBM)  { lb = b - kBA;        A = hM; WT = WpW1T + 1ull*kDE*kDIN;  typeN = kNM; rowBase = kNA; }
    else                     { lb = b - kBA - kBM;  A = hT; WT = WpW1T + 2ull*kDE*kDIN;  typeN = kNT; rowBase = kNA + kNM; }
    int r0 = lb * 4, col = threadIdx.x;
    const float* wcol = WT + (size_t)col * kDIN;
    float acc[4] = {0.f, 0.f, 0.f, 0.f};
    for (int k = 0; k < kDIN; k += 8) {
        const float4 w0 = *(const float4*)(wcol + k);
        const float4 w1 = *(const float4*)(wcol + k + 4);
#pragma unroll
        for (int r = 0; r < 4; r++) {
            int gr = min(r0 + r, typeN - 1);                  // uniform -> s_load
            const float4 a0 = *(const float4*)(A + (size_t)gr * kDIN + k);
            const float4 a1 = *(const float4*)(A + (size_t)gr * kDIN + k + 4);
            acc[r] += a0.x * w0.x + a0.y * w0.y + a0.z * w0.z + a0.w * w0.w
                    + a1.x * w1.x + a1.y * w1.y + a1.z * w1.z + a1.w * w1.w;
        }
    }
#pragma unroll
    for (int r = 0; r < 4; r++) {
        int lr = r0 + r;
        if (lr < typeN) HW1[(size_t)(rowBase + lr) * kDE + col] = acc[r];
    }
}

// ---- CSR build (clamped) ----
__device__ __forceinline__ int clampN(int v) { return min(max(v, 0), kN - 1); }

__global__ __launch_bounds__(256) void hist_kernel(const int* __restrict__ key,
                                                   int* __restrict__ counts)
{
    int e = blockIdx.x * 256 + threadIdx.x;
    if (e < kE) atomicAdd(&counts[clampN(key[e])], 1);
}

__global__ __launch_bounds__(256) void scan_kernel(int* __restrict__ cnt_cur,
                                                   int* __restrict__ rowptr)
{
    __shared__ int sums[256];
    int tid = threadIdx.x;
    int i0 = tid * 63, i1 = min(i0 + 63, kN);
    int s = 0;
    for (int i = i0; i < i1; i++) s += cnt_cur[i];
    sums[tid] = s;
    __syncthreads();
    if (tid == 0) {
        int run = 0;
        for (int i = 0; i < 256; i++) { int v = sums[i]; sums[i] = run; run += v; }
    }
    __syncthreads();
    int base = sums[tid];
    for (int i = i0; i < i1; i++) {
        int c = cnt_cur[i];
        rowptr[i] = base;
        cnt_cur[i] = base;       // becomes fill cursor
        base += c;
    }
    if (tid == 0) rowptr[kN] = kE;
}

__global__ __launch_bounds__(256) void fill_kernel(const int* __restrict__ stored,
                                                   const int* __restrict__ key,
                                                   int* __restrict__ cursor,
                                                   int* __restrict__ esrc)
{
    int e = blockIdx.x * 256 + threadIdx.x;
    if (e < kE) {
        int p = atomicAdd(&cursor[clampN(key[e])], 1);
        esrc[min(p, kE - 1)] = clampN(stored[e]);
    }
}

// ---- agg1 fused: h1[n] = relu(sum_{e:dst==n} HW1[src[e]] + b1); 4-way MLP ----
__global__ __launch_bounds__(kDE) void agg_relu_kernel(const float* __restrict__ X,
                                                       const int* __restrict__ rowptr,
                                                       const int* __restrict__ esrc,
                                                       const float* __restrict__ b1,
                                                       float* __restrict__ out)
{
    int n = blockIdx.x, tid = threadIdx.x;
    int j = rowptr[n], end = rowptr[n + 1];
    float a0 = 0.f, a1 = 0.f, a2 = 0.f, a3 = 0.f;
    for (; j + 3 < end; j += 4) {
        int s0 = esrc[j], s1 = esrc[j + 1], s2 = esrc[j + 2], s3 = esrc[j + 3];
        a0 += X[(size_t)s0 * kDE + tid];
        a1 += X[(size_t)s1 * kDE + tid];
        a2 += X[(size_t)s2 * kDE + tid];
        a3 += X[(size_t)s3 * kDE + tid];
    }
    for (; j < end; j++) a0 += X[(size_t)esrc[j] * kDE + tid];
    out[(size_t)n * kDE + tid] = fmaxf((a0 + a1) + (a2 + a3) + b1[tid], 0.f);
}

// ---- agg2: plain segment sum; 4-way MLP ----
__global__ __launch_bounds__(kDE) void agg_kernel(const float* __restrict__ X,
                                                  const int* __restrict__ rowptr,
                                                  const int* __restrict__ esrc,
                                                  float* __restrict__ out)
{
    int n = blockIdx.x, tid = threadIdx.x;
    int j = rowptr[n], end = rowptr[n + 1];
    float a0 = 0.f, a1 = 0.f, a2 = 0.f, a3 = 0.f;
    for (; j + 3 < end; j += 4) {
        int s0 = esrc[j], s1 = esrc[j + 1], s2 = esrc[j + 2], s3 = esrc[j + 3];
        a0 += X[(size_t)s0 * kDE + tid];
        a1 += X[(size_t)s1 * kDE + tid];
        a2 += X[(size_t)s2 * kDE + tid];
        a3 += X[(size_t)s3 * kDE + tid];
    }
    for (; j < end; j++) a0 += X[(size_t)esrc[j] * kDE + tid];
    out[(size_t)n * kDE + tid] = (a0 + a1) + (a2 + a3);
}

// ---- gemm2 + L2-normalize fused: hn = normalize(agg2 @ W2 + b2); writes h + h_movie ----
__global__ __launch_bounds__(kDE) void gemm2_norm_kernel(
    const float* __restrict__ X, const float* __restrict__ W2T,
    const float* __restrict__ b2, float* __restrict__ hn,
    float* __restrict__ out)
{
    int r0 = blockIdx.x * 4;
    int col = threadIdx.x;
    const float* wcol = W2T + (size_t)col * kDE;
    float acc[4] = {0.f, 0.f, 0.f, 0.f};
    for (int k = 0; k < kDE; k += 8) {
        const float4 w0 = *(const float4*)(wcol + k);
        const float4 w1 = *(const float4*)(wcol + k + 4);
#pragma unroll
        for (int r = 0; r < 4; r++) {
            int gr = min(r0 + r, kN - 1);                     // uniform -> s_load
            const float4 a0 = *(const float4*)(X + (size_t)gr * kDE + k);
            const float4 a1 = *(const float4*)(X + (size_t)gr * kDE + k + 4);
            acc[r] += a0.x * w0.x + a0.y * w0.y + a0.z * w0.z + a0.w * w0.w
                    + a1.x * w1.x + a1.y * w1.y + a1.z * w1.z + a1.w * w1.w;
        }
    }
    float bv = b2[col];
    float v[4];
#pragma unroll
    for (int r = 0; r < 4; r++) v[r] = acc[r] + bv;

    // per-row sum of squares across 128 threads (2 waves)
    __shared__ float red[4][2];
    int wave = col >> 6;
#pragma unroll
    for (int r = 0; r < 4; r++) {
        float ss = v[r] * v[r];
#pragma unroll
        for (int o = 32; o > 0; o >>= 1) ss += __shfl_xor(ss, o);
        if ((col & 63) == 0) red[r][wave] = ss;
    }
    __syncthreads();
#pragma unroll
    for (int r = 0; r < 4; r++) {
        int gr = r0 + r;
        if (gr >= kN) break;
        float tot = red[r][0] + red[r][1];
        float sc = 1.f / fmaxf(sqrtf(tot), 1e-12f);
        float hv = v[r] * sc;
        hn[(size_t)gr * kDE + col] = hv;
        out[(size_t)gr * kDE + col] = hv;
        if (gr >= kNA && gr < kNA + kNM)
            out[OUT_HM + (size_t)(gr - kNA) * kDE + col] = hv;
    }
}

// ---- partial tables: P[g][n][16] = hn[n] @ M9[g][type(n)] ----
__global__ __launch_bounds__(128) void partial_kernel(const float* __restrict__ hn,
                                                      const float* __restrict__ M9,
                                                      float* __restrict__ P)
{
    int b = blockIdx.x;
    int g = b / 2005, b2 = b % 2005;
    int t, lb, typeN, rowBase;
    if (b2 < 545)       { t = 0; lb = b2;        typeN = kNA; rowBase = 0; }
    else if (b2 < 1005) { t = 1; lb = b2 - 545;  typeN = kNM; rowBase = kNA; }
    else                { t = 2; lb = b2 - 1005; typeN = kNT; rowBase = kNA + kNM; }
    const float* M = M9 + (size_t)(g * 3 + t) * 2048;
    int r = threadIdx.x >> 4, j = threadIdx.x & 15;
    int lr = lb * 8 + r;
    if (lr >= typeN) return;
    int n = rowBase + lr;
    float acc = 0.f;
    for (int k = 0; k < kDE; k += 4) {
        const float4 h4 = *(const float4*)(hn + (size_t)n * kDE + k);
        acc += h4.x * M[(k + 0) * 16 + j] + h4.y * M[(k + 1) * 16 + j]
             + h4.z * M[(k + 2) * 16 + j] + h4.w * M[(k + 3) * 16 + j];
    }
    P[((size_t)g * kN + n) * 16 + j] = acc;
}

// ---- classifier-lite: 3 x 16-float gathers + relu-dot + sigmoid ----
__global__ __launch_bounds__(256) void cls_lite_kernel(
    const float* __restrict__ P,
    const int* __restrict__ n0a, const int* __restrict__ n0m, const int* __restrict__ n0t,
    const int* __restrict__ n1a, const int* __restrict__ n1m, const int* __restrict__ n1t,
    const int* __restrict__ n2a, const int* __restrict__ n2m, const int* __restrict__ n2t,
    const float* __restrict__ WoA, const float* __restrict__ WoM, const float* __restrict__ WoT,
    float* __restrict__ out, int blocksPerGroup)
{
    int g = blockIdx.x / blocksPerGroup;
    int i = (blockIdx.x % blocksPerGroup) * 256 + threadIdx.x;
    if (i >= kS) return;
    auto cA = [](int v){ return min(max(v, 0), kNA - 1); };
    auto cM = [](int v){ return min(max(v, 0), kNM - 1); };
    auto cT = [](int v){ return min(max(v, 0), kNT - 1); };
    int ra, rb, rc;
    if (g == 0)      { ra = cA(n0a[i]);             rb = kNA + cM(n0m[i]);  rc = kNA + kNM + cT(n0t[i]); }
    else if (g == 1) { ra = kNA + cM(n1m[i]);       rb = cA(n1a[i]);        rc = kNA + kNM + cT(n1t[i]); }
    else             { ra = kNA + kNM + cT(n2t[i]); rb = cA(n2a[i]);        rc = kNA + cM(n2m[i]); }
    const float* Pg = P + (size_t)g * kN * 16;
    const float* wo = (g == 0) ? WoA : ((g == 1) ? WoM : WoT);   // uniform -> s_load
    const float4* pa = (const float4*)(Pg + (size_t)ra * 16);
    const float4* pb = (const float4*)(Pg + (size_t)rb * 16);
    const float4* pc = (const float4*)(Pg + (size_t)rc * 16);
    float p = 0.f;
#pragma unroll
    for (int q = 0; q < 4; q++) {
        float4 a = pa[q], b = pb[q], c = pc[q];
        p += fmaxf(a.x + b.x + c.x, 0.f) * wo[q * 4 + 0];
        p += fmaxf(a.y + b.y + c.y, 0.f) * wo[q * 4 + 1];
        p += fmaxf(a.z + b.z + c.z, 0.f) * wo[q * 4 + 2];
        p += fmaxf(a.w + b.w + c.w, 0.f) * wo[q * 4 + 3];
    }
    out[OUT_X + (size_t)g * kS + i] = 1.f / (1.f + expf(-p));
}

extern "C" void kernel_launch(void* const* d_in, const int* in_sizes, int n_in,
                              void* d_out, int out_size, void* d_ws, size_t ws_size,
                              hipStream_t stream)
{
    (void)out_size;
    static const int expected[30] = {
        2228736, 1882112, 4096000, 131072, 131072, 131072, 32768, 128, 16384, 128,
        8192, 8192, 8192, 4096, 4096, 4096, 16, 16, 16,
        500000, 500000, 200000, 200000, 200000, 200000, 200000, 200000, 200000, 200000, 200000 };
    if (n_in != 30) return;
    for (int i = 0; i < 30; i++) if (in_sizes[i] != expected[i]) return;
    if (ws_size < WS_NEEDED) return;

    // inputs proven f32 / int32 (rounds 7-10)
    const float* h_a  = (const float*)d_in[0];
    const float* h_m  = (const float*)d_in[1];
    const float* h_t  = (const float*)d_in[2];
    const float* Wp_a = (const float*)d_in[3];
    const float* Wp_m = (const float*)d_in[4];
    const float* Wp_t = (const float*)d_in[5];
    const float* W1   = (const float*)d_in[6];
    const float* b1   = (const float*)d_in[7];
    const float* W2   = (const float*)d_in[8];
    const float* b2   = (const float*)d_in[9];
    const float* Wc_a = (const float*)d_in[10];
    const float* Wc_m = (const float*)d_in[11];
    const float* Wc_t = (const float*)d_in[12];
    const float* Wh_a = (const float*)d_in[13];
    const float* Wh_m = (const float*)d_in[14];
    const float* Wh_t = (const float*)d_in[15];
    const float* Wo_a = (const float*)d_in[16];
    const float* Wo_m = (const float*)d_in[17];
    const float* Wo_t = (const float*)d_in[18];
    const int* src = (const int*)d_in[19];
    const int* dst = (const int*)d_in[20];

    char* ws = (char*)d_ws;
    float* WpW1T = (float*)(ws + OFF_WPW1T);
    float* M9    = (float*)(ws + OFF_M9);
    float* W2T   = (float*)(ws + OFF_W2T);
    float* HW1   = (float*)(ws + OFF_HW1);
    float* h1    = (float*)(ws + OFF_H1);
    float* agg2  = (float*)(ws + OFF_AGG2);
    float* hn    = (float*)(ws + OFF_HN);
    float* P     = (float*)(ws + OFF_P);
    int* esrc    = (int*)(ws + OFF_ESRC);
    int* rowptr  = (int*)(ws + OFF_RP);
    int* cursor  = (int*)(ws + OFF_CUR);
    float* out   = (float*)d_out;

    hipMemsetAsync(cursor, 0, (size_t)kN * 4, stream);

    hist_kernel<<<dim3(1954), dim3(256), 0, stream>>>(dst, cursor);
    scan_kernel<<<dim3(1), dim3(256), 0, stream>>>(cursor, rowptr);
    fill_kernel<<<dim3(1954), dim3(256), 0, stream>>>(src, dst, cursor, esrc);

    prep1_kernel<<<dim3(384), dim3(128), 0, stream>>>(Wp_a, Wp_m, Wp_t, W1, WpW1T);
    prep2_kernel<<<dim3(9), dim3(256), 0, stream>>>(Wh_a, Wh_m, Wh_t, Wc_a, Wc_m, Wc_t, M9);
    w2t_kernel<<<dim3(64), dim3(256), 0, stream>>>(W2, W2T);

    hw1_kernel<<<dim3(kHW1Blocks), dim3(128), 0, stream>>>(h_a, h_m, h_t, WpW1T, HW1);
    agg_relu_kernel<<<dim3(kN), dim3(kDE), 0, stream>>>(HW1, rowptr, esrc, b1, h1);
    agg_kernel<<<dim3(kN), dim3(kDE), 0, stream>>>(h1, rowptr, esrc, agg2);
    gemm2_norm_kernel<<<dim3(kG2Blocks), dim3(kDE), 0, stream>>>(agg2, W2T, b2, hn, out);
    partial_kernel<<<dim3(6015), dim3(128), 0, stream>>>(hn, M9, P);
    cls_lite_kernel<<<dim3(2346), dim3(256), 0, stream>>>(P,
        (const int*)d_in[21], (const int*)d_in[22], (const int*)d_in[23],
        (const int*)d_in[24], (const int*)d_in[25], (const int*)d_in[26],
        (const int*)d_in[27], (const int*)d_in[28], (const int*)d_in[29],
        Wo_a, Wo_m, Wo_t, out, 782);
}